// Round 5
// baseline (431.251 us; speedup 1.0000x reference)
//
#include <hip/hip_runtime.h>

// Fused LocalSelfAttention (Swin ws=8, nh=16, hd=32), B=16 N=4096 C=512.
// v5: minimal-weight-traffic restructure. 1024-thr block = 1 window.
//   - 2 passes x 8 heads. GEMM1: all 16 waves, wave=(head hh=wave>>1, tri=wave&1),
//     mA=4 (all 64 tokens) x nB=3 tiles -> 12 MFMA/kk, each qkv B-tile loaded
//     EXACTLY once per block (1.5 MB, v4 was 3 MB): L2 traffic at its floor.
//   - proj fused per pass (K=256 chunk, kkl 0..7), pacc[4][2] in all 16 waves.
//   - GEMM1(p+1) compute (reads xw+global only) issued BEFORE the pass-top
//     barrier -> overlaps proj(p) tail across waves.
//   - attention wave=(hh, tri as q-half): serial qt loop (register headroom),
//     softmax in-lane (15 fmax + 2 shfl), inv deferred to O-scale.
//   - LDS 160 KB exact: xw 64K | scr 8 x {q 4K,k 4K,vT 4K} = 96K; ob (32K,
//     [64 tok][256 ch]) overlays scr heads 0-2 between s2/s3 and next staging.
//   - ob swizzle ^((tok&7)<<6) on 512B rows: <=2-way on store and proj read.
//   - 8 barriers/block total.

typedef short s16x8 __attribute__((ext_vector_type(8)));
typedef float f32x4 __attribute__((ext_vector_type(4)));

union V8 { uint4 u4; uint2 u2[2]; s16x8 h; ushort s[8]; uint u[4]; };

__device__ __forceinline__ ushort f2b(float f) {
    union { float f; uint u; } v; v.f = f;
    return (ushort)((v.u + 0x7fffu + ((v.u >> 16) & 1u)) >> 16);  // RNE
}
__device__ __forceinline__ void cvt8(const float* __restrict__ p, V8& d) {
    union { float4 f; uint u[4]; } a, b;
    a.f = *(const float4*)p;  b.f = *(const float4*)(p + 4);
    d.u[0] = __builtin_amdgcn_perm(a.u[1], a.u[0], 0x07060302u);
    d.u[1] = __builtin_amdgcn_perm(a.u[3], a.u[2], 0x07060302u);
    d.u[2] = __builtin_amdgcn_perm(b.u[1], b.u[0], 0x07060302u);
    d.u[3] = __builtin_amdgcn_perm(b.u[3], b.u[2], 0x07060302u);
}
__device__ __forceinline__ f32x4 mfma16(s16x8 a, s16x8 b, f32x4 c) {
    return __builtin_amdgcn_mfma_f32_16x16x32_bf16(a, b, c, 0, 0, 0);
}
__device__ __forceinline__ uint2 pack4(float a, float b, float c, float d) {
    uint2 r;
    r.x = (uint)f2b(a) | ((uint)f2b(b) << 16);
    r.y = (uint)f2b(c) | ((uint)f2b(d) << 16);
    return r;
}

// ---------------------------------------------------------------------------
// Prologue: fp32 weights -> bf16 in MFMA-fragment order (unchanged).
// qkv tiles 0..95 (mat*32+ntile) at ws[0..786432); proj tiles 0..31 at
// ws[786432..1048576). Per (tile,kk): 512-short block, element
// (quad*128 + colw*8 + j) = w[n=tile*16+colw][k=kk*32+quad*8+j].
// ---------------------------------------------------------------------------
__global__ __launch_bounds__(256)
void pack_w(const float* __restrict__ wqkv, const float* __restrict__ wproj,
            ushort* __restrict__ dst)
{
    const int gid = blockIdx.x * 256 + threadIdx.x;   // 131072 threads
    const int o = gid << 3;
    const int colw = (o >> 3) & 15, quad = (o >> 7) & 3, kk = (o >> 9) & 15;
    const int tile = o >> 13;
    const float* src;
    if (o < 786432) {
        const int mat = tile >> 5, nt = tile & 31;
        src = wqkv + (size_t)(mat * 512 + nt * 16 + colw) * 512 + (kk << 5) + (quad << 3);
    } else {
        const int nt = tile - 96;
        src = wproj + (size_t)(nt * 16 + colw) * 512 + (kk << 5) + (quad << 3);
    }
    float4 a = *(const float4*)src, b = *(const float4*)(src + 4);
    V8 v;
    v.s[0] = f2b(a.x); v.s[1] = f2b(a.y); v.s[2] = f2b(a.z); v.s[3] = f2b(a.w);
    v.s[4] = f2b(b.x); v.s[5] = f2b(b.y); v.s[6] = f2b(b.z); v.s[7] = f2b(b.w);
    *(uint4*)(dst + o) = v.u4;
}

// ---------------------------------------------------------------------------
// Fused kernel. PK=true: packed bf16 weights in ws. PK=false: fp32 fallback.
// ---------------------------------------------------------------------------
template<bool PK>
__global__ __launch_bounds__(1024, 4)
void win_fused(const float* __restrict__ x, const void* __restrict__ Wq,
               const void* __restrict__ Wp, const float* __restrict__ bproj,
               float* __restrict__ out)
{
    __shared__ __align__(16) ushort sm[81920];     // 163840 B = full LDS pool
    ushort* const xw = sm;                         // [64 tok][512 ch] swizzled, 64K
    char* const sb = (char*)(sm + 32768);          // scr: 8 x 12288 B; ob overlays [0,32768)

    const int tid  = threadIdx.x;
    const int lane = tid & 63;
    const int wave = tid >> 6;           // 0..15
    const int col  = lane & 15, quad = lane >> 4;
    const int win  = blockIdx.x;
    const int bb = win >> 6, wh = (win >> 3) & 7, ww = win & 7;
    const size_t xbase = (size_t)(bb * 4096) * 512;

    // ---------------- gather (scrambled window partition), fp32 -> bf16 ------
    {
        const int m8 = lane;              // channel-oct
        const int u8 = wave & 7;          // spatial row in window
        const int dh = wave >> 3;         // du half
        const int t  = ((m8 & 7) << 3) | (m8 >> 3);
        const int ch0 = m8 << 3;
        const float* gp = x + xbase
            + (size_t)(wh * 512 + u8 * 64 + ww * 8 + dh * 4) * 512 + ch0;
        V8 L[4];
        #pragma unroll
        for (int i = 0; i < 4; ++i) cvt8(gp + i * 512, L[i]);
        #pragma unroll
        for (int e = 0; e < 8; ++e) {
            union { uint2 u; ushort s[4]; } Wv;
            #pragma unroll
            for (int i = 0; i < 4; ++i) Wv.s[i] = L[i].s[e];
            const int c8 = (e << 3) | u8;
            *(uint2*)(&xw[(t << 9) + ((c8 ^ (t & 7)) << 3) + (dh << 2)]) = Wv.u;
        }
    }
    __syncthreads();

    const int hh  = wave >> 1;           // head-in-pass 0..7
    const int tri = wave & 1;            // GEMM1 tile-triple / attention q-half

    f32x4 pacc[4][2];                    // proj acc: 4 tok-tiles x 2 out-16col tiles
    #pragma unroll
    for (int mt = 0; mt < 4; ++mt) {
        pacc[mt][0] = (f32x4){0.f, 0.f, 0.f, 0.f};
        pacc[mt][1] = (f32x4){0.f, 0.f, 0.f, 0.f};
    }
    const float smul = 0.17677669529663689f * 1.4426950408889634f;  // scale*log2e

    for (int p = 0; p < 2; ++p) {
        const int h = (p << 3) | hh;

        // ---- GEMM1: M=64 (all tokens) x 3 n-tiles, K=512; B loaded once ----
        f32x4 c[4][3];
        #pragma unroll
        for (int mt = 0; mt < 4; ++mt)
            #pragma unroll
            for (int nt = 0; nt < 3; ++nt) c[mt][nt] = (f32x4){0.f, 0.f, 0.f, 0.f};
        size_t wb0 = 0, wb1 = 0, wb2 = 0;
        const float *f0 = nullptr, *f1 = nullptr, *f2 = nullptr;
        if constexpr (PK) {
            if (tri == 0) { wb0 = (size_t)(2*h)     * 8192; wb1 = (size_t)(2*h+1)  * 8192;
                            wb2 = (size_t)(32+2*h)  * 8192; }
            else          { wb0 = (size_t)(32+2*h+1)* 8192; wb1 = (size_t)(64+2*h) * 8192;
                            wb2 = (size_t)(64+2*h+1)* 8192; }
        } else {
            const float* W = (const float*)Wq;
            if (tri == 0) {
                f0 = W + (size_t)(h*32 + col) * 512;
                f1 = W + (size_t)(h*32 + 16 + col) * 512;
                f2 = W + (size_t)(512 + h*32 + col) * 512;
            } else {
                f0 = W + (size_t)(512 + h*32 + 16 + col) * 512;
                f1 = W + (size_t)(1024 + h*32 + col) * 512;
                f2 = W + (size_t)(1024 + h*32 + 16 + col) * 512;
            }
        }
        #pragma unroll 2
        for (int kk = 0; kk < 16; ++kk) {
            const int c8 = (kk << 2) | quad;
            V8 b0, b1, b2;
            if constexpr (PK) {
                const ushort* W = (const ushort*)Wq;
                const int lo = (kk << 9) + (lane << 3);
                b0.u4 = *(const uint4*)(&W[wb0 + lo]);
                b1.u4 = *(const uint4*)(&W[wb1 + lo]);
                b2.u4 = *(const uint4*)(&W[wb2 + lo]);
            } else {
                cvt8(f0 + (kk << 5) + (quad << 3), b0);
                cvt8(f1 + (kk << 5) + (quad << 3), b1);
                cvt8(f2 + (kk << 5) + (quad << 3), b2);
            }
            #pragma unroll
            for (int mt = 0; mt < 4; ++mt) {
                const int t = (mt << 4) + col;
                V8 a; a.u4 = *(const uint4*)(&xw[(t << 9) + ((c8 ^ (t & 7)) << 3)]);
                c[mt][0] = mfma16(a.h, b0.h, c[mt][0]);
                c[mt][1] = mfma16(a.h, b1.h, c[mt][1]);
                c[mt][2] = mfma16(a.h, b2.h, c[mt][2]);
            }
        }

        if (p) __syncthreads();   // sA: prior-pass proj reads done before staging

        // ---- stage q/k (scalar u16) + vT (uint2) into head region ----
        {
            const int hb = hh * 12288;
            if (tri == 0) {
                #pragma unroll
                for (int mt = 0; mt < 4; ++mt)
                    #pragma unroll
                    for (int r = 0; r < 4; ++r) {
                        const int tok  = (mt << 4) + (quad << 2) + r;
                        const int rowb = hb + (tok << 6);
                        const int s    = quad << 4;
                        *(ushort*)(sb + rowb + ((col*2)        ^ s)) = f2b(c[mt][0][r]);
                        *(ushort*)(sb + rowb + ((32 + col*2)   ^ s)) = f2b(c[mt][1][r]);
                        *(ushort*)(sb + 4096 + rowb + ((col*2) ^ s)) = f2b(c[mt][2][r]);
                    }
            } else {
                #pragma unroll
                for (int mt = 0; mt < 4; ++mt) {
                    #pragma unroll
                    for (int r = 0; r < 4; ++r) {
                        const int tok = (mt << 4) + (quad << 2) + r;
                        *(ushort*)(sb + hb + 4096 + (tok << 6)
                                   + ((32 + col*2) ^ (quad << 4))) = f2b(c[mt][0][r]);
                    }
                    const int tok0 = (mt << 4) + (quad << 2);
                    const int tsw  = (tok0 * 2) ^ ((col & 7) << 4);
                    *(uint2*)(sb + hb + 8192 + col * 128        + tsw) =
                        pack4(c[mt][1][0], c[mt][1][1], c[mt][1][2], c[mt][1][3]);
                    *(uint2*)(sb + hb + 8192 + (16 + col) * 128 + tsw) =
                        pack4(c[mt][2][0], c[mt][2][1], c[mt][2][2], c[mt][2][3]);
                }
            }
        }
        __syncthreads();   // s1: q/k/vT of all 8 heads visible

        // ---- attention: wave = (head hh, q-half tri); qt serial ----
        {
            const int ab = hh * 12288;
            const int sr = ((col >> 2) & 3) << 4;
            s16x8 kf[4];
            #pragma unroll
            for (int kt = 0; kt < 4; ++kt) {
                V8 v; v.u4 = *(const uint4*)(sb + ab + 4096
                              + (((kt << 4) + col) << 6) + ((quad << 4) ^ sr));
                kf[kt] = v.h;
            }
            float inv[2]; uint2 pk[4][2];
            #pragma unroll
            for (int qt = 0; qt < 2; ++qt) {
                V8 qf; qf.u4 = *(const uint4*)(sb + ab
                               + ((((tri*2 + qt) << 4) + col) << 6) + ((quad << 4) ^ sr));
                f32x4 ST[4];
                #pragma unroll
                for (int kt = 0; kt < 4; ++kt)
                    ST[kt] = mfma16(kf[kt], qf.h, (f32x4){0.f,0.f,0.f,0.f});
                float m0 = ST[0][0];
                #pragma unroll
                for (int kt = 0; kt < 4; ++kt)
                    #pragma unroll
                    for (int r = 0; r < 4; ++r) m0 = fmaxf(m0, ST[kt][r]);
                m0 = fmaxf(m0, __shfl_xor(m0, 16));
                m0 = fmaxf(m0, __shfl_xor(m0, 32));
                float s0 = 0.f;
                #pragma unroll
                for (int kt = 0; kt < 4; ++kt)
                    #pragma unroll
                    for (int r = 0; r < 4; ++r) {
                        const float pv = exp2f((ST[kt][r] - m0) * smul);
                        ST[kt][r] = pv; s0 += pv;
                    }
                s0 += __shfl_xor(s0, 16);
                s0 += __shfl_xor(s0, 32);
                inv[qt] = 1.0f / s0;
                #pragma unroll
                for (int kt = 0; kt < 4; ++kt)
                    pk[kt][qt] = pack4(ST[kt][0], ST[kt][1], ST[kt][2], ST[kt][3]);
            }

            // PV: both d-halves, both q-tiles; P-frags via intra-wave shuffle
            f32x4 OT[2][2];
            #pragma unroll
            for (int dt = 0; dt < 2; ++dt) {
                OT[dt][0] = (f32x4){0.f,0.f,0.f,0.f};
                OT[dt][1] = (f32x4){0.f,0.f,0.f,0.f};
            }
            const int srcA = ((quad & 1) << 5) + col;
            const int srcB = srcA + 16;
            const bool hi = quad >= 2;
            const int vsw = (col & 7) << 4;
            #pragma unroll
            for (int kh = 0; kh < 2; ++kh) {
                s16x8 pf[2];
                #pragma unroll
                for (int qt = 0; qt < 2; ++qt) {
                    const uint2 pkA = pk[kh*2][qt], pkB = pk[kh*2+1][qt];
                    const uint a0x = __shfl((int)pkA.x, srcA), a0y = __shfl((int)pkA.y, srcA);
                    const uint b0x = __shfl((int)pkA.x, srcB), b0y = __shfl((int)pkA.y, srcB);
                    const uint a1x = __shfl((int)pkB.x, srcA), a1y = __shfl((int)pkB.y, srcA);
                    const uint b1x = __shfl((int)pkB.x, srcB), b1y = __shfl((int)pkB.y, srcB);
                    V8 t;
                    t.u[0] = hi ? a1x : a0x;  t.u[1] = hi ? a1y : a0y;
                    t.u[2] = hi ? b1x : b0x;  t.u[3] = hi ? b1y : b0y;
                    pf[qt] = t.h;
                }
                #pragma unroll
                for (int dt = 0; dt < 2; ++dt) {
                    V8 vf; vf.u4 = *(const uint4*)(sb + ab + 8192
                                   + (((dt << 4) + col) << 7)
                                   + (((kh << 6) + (quad << 4)) ^ vsw));
                    OT[dt][0] = mfma16(vf.h, pf[0], OT[dt][0]);
                    OT[dt][1] = mfma16(vf.h, pf[1], OT[dt][1]);
                }
            }
            __syncthreads();   // s2: all scr reads done; ob may overlay

            // ---- o (scaled) -> ob[64 tok][256 ch] @ scr+0, swizzled ----
            #pragma unroll
            for (int dt = 0; dt < 2; ++dt)
                #pragma unroll
                for (int qt = 0; qt < 2; ++qt) {
                    const int tok   = ((tri*2 + qt) << 4) + col;
                    const int choff = (hh << 6) + (dt << 5) + (quad << 3);  // 2*ch0
                    *(uint2*)(sb + (tok << 9) + (choff ^ ((col & 7) << 6))) =
                        pack4(OT[dt][qt][0]*inv[qt], OT[dt][qt][1]*inv[qt],
                              OT[dt][qt][2]*inv[qt], OT[dt][qt][3]*inv[qt]);
                }
        }
        __syncthreads();   // s3: ob complete

        // ---- proj partial: K-chunk = pass's 256 ch; wave owns 32 out cols ----
        #pragma unroll 2
        for (int kkl = 0; kkl < 8; ++kkl) {
            const int kkg = (p << 3) | kkl;
            V8 a[4];
            const int osw = (col & 7) << 6;
            #pragma unroll
            for (int mt = 0; mt < 4; ++mt)
                a[mt].u4 = *(const uint4*)(sb + (((mt << 4) + col) << 9)
                            + (((kkl << 6) + (quad << 4)) ^ osw));
            #pragma unroll
            for (int nt = 0; nt < 2; ++nt) {
                s16x8 b;
                if constexpr (PK) {
                    const ushort* W = (const ushort*)Wp;
                    V8 v; v.u4 = *(const uint4*)(&W[(size_t)(((wave*2 + nt) << 4) + kkg) * 512
                                                    + (lane << 3)]);
                    b = v.h;
                } else {
                    const float* W = (const float*)Wp;
                    V8 v; cvt8(W + (size_t)(wave*32 + (nt << 4) + col) * 512
                                 + (kkg << 5) + (quad << 3), v);
                    b = v.h;
                }
                #pragma unroll
                for (int mt = 0; mt < 4; ++mt)
                    pacc[mt][nt] = mfma16(a[mt].h, b, pacc[mt][nt]);
            }
        }
        // no barrier: next pass's GEMM1 reads only xw/global; sA(p+1) fences
        // these ob reads before staging overwrites scr.
    }

    // ---------------- epilogue: bias + fp32 out at merged positions ----------
    const size_t wbase = (size_t)(bb * 4096 + wh * 512 + ww * 8) * 512;
    const float bv0 = bproj[wave*32 + col];
    const float bv1 = bproj[wave*32 + 16 + col];
    #pragma unroll
    for (int mt = 0; mt < 4; ++mt)
        #pragma unroll
        for (int r = 0; r < 4; ++r) {
            const int t = (mt << 4) + (quad << 2) + r;
            float* op = out + wbase + (size_t)(((t >> 3) << 6) + (t & 7)) * 512
                        + wave*32;
            op[col]      = pacc[mt][0][r] + bv0;
            op[16 + col] = pacc[mt][1][r] + bv1;
        }
}

extern "C" void kernel_launch(void* const* d_in, const int* in_sizes, int n_in,
                              void* d_out, int out_size, void* d_ws, size_t ws_size,
                              hipStream_t stream) {
    const float* x     = (const float*)d_in[0];
    const float* wqkv  = (const float*)d_in[1];
    const float* wproj = (const float*)d_in[2];
    const float* bproj = (const float*)d_in[3];
    float* out = (float*)d_out;
    (void)in_sizes; (void)n_in; (void)out_size;

    if (ws_size >= 2097152) {
        ushort* wpk = (ushort*)d_ws;
        pack_w<<<dim3(512), dim3(256), 0, stream>>>(wqkv, wproj, wpk);
        win_fused<true><<<dim3(1024), dim3(1024), 0, stream>>>(
            x, wpk, wpk + 786432, bproj, out);
    } else {
        win_fused<false><<<dim3(1024), dim3(1024), 0, stream>>>(
            x, wqkv, wproj, bproj, out);
    }
}